// Round 5
// baseline (166.048 us; speedup 1.0000x reference)
//
#include <hip/hip_runtime.h>
#include <hip/hip_bf16.h>

// DendriticLayerSiLU: out = silu(softmax-gated template proj) * (x @ W^T)
// N=4096 tokens, K=2048, H=1024, 32 windows of 64.
// Round 5: 32x32x16 MFMA (2x FLOP per LDS byte), X direct global->VGPR
// (LDS holds only W/T), wave tile 32x64, block 64x256, 96 KB LDS dbuf.

typedef __attribute__((ext_vector_type(8))) short short8;
typedef __attribute__((ext_vector_type(4))) float f32x4;
typedef __attribute__((ext_vector_type(16))) float f32x16;

#define N_TOK 4096
#define K_DIM 2048
#define H_DIM 1024
#define BM 64
#define BH 256
#define BK 32

#define X_ELEMS (N_TOK * K_DIM)   // 8388608
#define W_ELEMS (H_DIM * K_DIM)   // 2097152
#define WS_NEED ((size_t)(2 * X_ELEMS + 3 * W_ELEMS) * 2)  // 46,137,344 B

#define XB (X_ELEMS / 8 / 256)    // 4096 prepass blocks for X
#define WB (W_ELEMS / 8 / 256)    // 1024 for W, 1024 for T

__device__ __forceinline__ unsigned short f2bf(float f) {
    unsigned int u = __float_as_uint(f);
    u += 0x7FFFu + ((u >> 16) & 1u);    // round-to-nearest-even
    return (unsigned short)(u >> 16);
}
__device__ __forceinline__ float bf2f(unsigned short h) {
    return __uint_as_float(((unsigned int)h) << 16);
}

__device__ __forceinline__ void cvt_split(f32x4 a, f32x4 b, short8& vh, short8& vl) {
#pragma unroll
    for (int i = 0; i < 4; ++i) {
        float f = a[i];
        unsigned short h = f2bf(f);
        vh[i] = (short)h;
        vl[i] = (short)f2bf(f - bf2f(h));
    }
#pragma unroll
    for (int i = 0; i < 4; ++i) {
        float f = b[i];
        unsigned short h = f2bf(f);
        vh[i + 4] = (short)h;
        vl[i + 4] = (short)f2bf(f - bf2f(h));
    }
}
__device__ __forceinline__ short8 cvt_hi(f32x4 a, f32x4 b) {
    short8 v;
#pragma unroll
    for (int i = 0; i < 4; ++i) { v[i] = (short)f2bf(a[i]); v[i + 4] = (short)f2bf(b[i]); }
    return v;
}

#define MFMA32(A, B, C) __builtin_amdgcn_mfma_f32_32x32x16_bf16(A, B, C, 0, 0, 0)
#define MFMA16(A, B, C) __builtin_amdgcn_mfma_f32_16x16x32_bf16(A, B, C, 0, 0, 0)

// ---------------------------------------------------------------- prepass ---
__global__ __launch_bounds__(256) void prepass_all(
    const float* __restrict__ X, const float* __restrict__ W,
    const float* __restrict__ T,
    unsigned short* __restrict__ XH, unsigned short* __restrict__ XL,
    unsigned short* __restrict__ WH, unsigned short* __restrict__ WL,
    unsigned short* __restrict__ TH)
{
    int b = blockIdx.x;
    if (b < XB + WB) {
        const float* src; unsigned short *hi, *lo; int i;
        if (b < XB) { src = X; hi = XH; lo = XL; i = b * 256 + threadIdx.x; }
        else        { src = W; hi = WH; lo = WL; i = (b - XB) * 256 + threadIdx.x; }
        const float* p = src + (size_t)i * 8;
        f32x4 a = *(const f32x4*)p;
        f32x4 c = *(const f32x4*)(p + 4);
        short8 vh, vl;
        cvt_split(a, c, vh, vl);
        *(short8*)&hi[(size_t)i * 8] = vh;
        *(short8*)&lo[(size_t)i * 8] = vl;
    } else {
        int i = (b - XB - WB) * 256 + threadIdx.x;
        const float* p = T + (size_t)i * 8;
        f32x4 a = *(const f32x4*)p;
        f32x4 c = *(const f32x4*)(p + 4);
        *(short8*)&TH[(size_t)i * 8] = cvt_hi(a, c);
    }
}

// ------------------------------------------------------------- main GEMM ----
#define GLL(gp, lp) __builtin_amdgcn_global_load_lds(                      \
        (const __attribute__((address_space(1))) void*)(gp),               \
        (__attribute__((address_space(3))) void*)(lp), 16, 0, 0)

__global__ __launch_bounds__(512, 2) void dend_gemm(
    const unsigned short* __restrict__ XH, const unsigned short* __restrict__ XL,
    const unsigned short* __restrict__ WH, const unsigned short* __restrict__ WL,
    const unsigned short* __restrict__ TH, float* __restrict__ O)
{
    // LDS: W/T only. arrays 0=w_hi 1=w_lo 2=t_hi, [256 rows][32 K], dbuf: 96KB
    __shared__ __align__(16) short ldsw[2][3][BH * BK];

    const int tid  = threadIdx.x;
    const int lane = tid & 63;
    const int wv   = tid >> 6;    // 0..7
    const int wm   = wv >> 2;     // 0..1  (32 token-rows each)
    const int wn   = wv & 3;      // 0..3  (64 unit-cols each)

    // grid 256 = 64 row-blocks x 4 col-panels; XCD k -> logicals [k*32,(k+1)*32)
    const int bid     = blockIdx.x;
    const int logical = (bid & 7) * 32 + (bid >> 3);
    const int hb   = logical >> 6;   // 0..3
    const int nb   = logical & 63;   // 0..63
    const int row0 = nb * BM;
    const int col0 = hb * BH;

    // ---- W/T staging (GLL linear dest + pre-swizzled global source).
    // LDS row = 64 B = 4 slots of 16B. Content(row, slot) = chunk slot^(row&3).
    // GLL: lane L -> row L>>2 (within 16-row stripe), slot L&3
    //   => global chunk = (L&3) ^ ((L>>2)&3).
    const int sc    = (lane & 3) ^ ((lane >> 2) & 3);
    const int wrow0 = wv * 32 + (lane >> 2);            // stripe 0 row
    const size_t wbase0 = (size_t)(col0 + wrow0) * K_DIM + sc * 8;
    const size_t wbase1 = wbase0 + (size_t)16 * K_DIM;  // stripe 1 (+16 rows)
    const int d0 = (wv * 32) * BK;                      // short index
    const int d1 = d0 + 16 * BK;

#define STAGE(buf, t) do {                                                 \
        const size_t ko = (size_t)(t) * BK;                                \
        GLL(WH + wbase0 + ko, &ldsw[buf][0][d0]);                          \
        GLL(WH + wbase1 + ko, &ldsw[buf][0][d1]);                          \
        GLL(WL + wbase0 + ko, &ldsw[buf][1][d0]);                          \
        GLL(WL + wbase1 + ko, &ldsw[buf][1][d1]);                          \
        GLL(TH + wbase0 + ko, &ldsw[buf][2][d0]);                          \
        GLL(TH + wbase1 + ko, &ldsw[buf][2][d1]);                          \
    } while (0)

    // ---- X register loads: 32x32x16 A-frag: lane L -> row L&31, k=(L>>5)*8+i
    const int xrow = row0 + wm * 32 + (lane & 31);
    const size_t xoff = (size_t)xrow * K_DIM + (lane >> 5) * 8;

#define LOADX(H0, H1, L0, L1, t) do {                                      \
        const size_t base = xoff + (size_t)(t) * BK;                       \
        H0 = *(const short8*)&XH[base];                                    \
        H1 = *(const short8*)&XH[base + 16];                               \
        L0 = *(const short8*)&XL[base];                                    \
        L1 = *(const short8*)&XL[base + 16];                               \
    } while (0)

    // ---- B read offsets (swizzled, conflict-free): B-frag row = unit col.
    int bo[2][2];
#pragma unroll
    for (int nj = 0; nj < 2; ++nj) {
        int r  = wn * 64 + nj * 32 + (lane & 31);
        int c0 = (lane >> 5);        // k-chunk for K 0..15
        int c1 = c0 | 2;             // k-chunk for K 16..31
        bo[nj][0] = r * BK + (c0 ^ (r & 3)) * 8;
        bo[nj][1] = r * BK + (c1 ^ (r & 3)) * 8;
    }

    const f32x16 zeroc = (f32x16)0.0f;
    f32x16 lin[2], num[2], den[2], win[2];
#pragma unroll
    for (int nj = 0; nj < 2; ++nj) {
        lin[nj] = zeroc; num[nj] = zeroc; den[nj] = zeroc; win[nj] = zeroc;
    }

#define COMPUTE(buf, H0, H1, L0, L1, ZW) do {                              \
        short8 bh[2][2], bl[2][2], bt[2][2];                               \
        _Pragma("unroll")                                                  \
        for (int nj = 0; nj < 2; ++nj)                                     \
        _Pragma("unroll")                                                  \
        for (int ch = 0; ch < 2; ++ch) {                                   \
            bh[nj][ch] = *(const short8*)&ldsw[buf][0][bo[nj][ch]];        \
            bl[nj][ch] = *(const short8*)&ldsw[buf][1][bo[nj][ch]];        \
            bt[nj][ch] = *(const short8*)&ldsw[buf][2][bo[nj][ch]];        \
        }                                                                  \
        _Pragma("unroll")                                                  \
        for (int nj = 0; nj < 2; ++nj) {                                   \
            lin[nj] = MFMA32(H0, bh[nj][0], lin[nj]);                      \
            lin[nj] = MFMA32(H1, bh[nj][1], lin[nj]);                      \
            lin[nj] = MFMA32(L0, bh[nj][0], lin[nj]);                      \
            lin[nj] = MFMA32(L1, bh[nj][1], lin[nj]);                      \
            lin[nj] = MFMA32(H0, bl[nj][0], lin[nj]);                      \
            lin[nj] = MFMA32(H1, bl[nj][1], lin[nj]);                      \
            win[nj] = MFMA32(H0, bt[nj][0], (ZW) ? zeroc : win[nj]);       \
            win[nj] = MFMA32(H1, bt[nj][1], win[nj]);                      \
        }                                                                  \
    } while (0)

#define EPILOG() do {                                                      \
        _Pragma("unroll")                                                  \
        for (int nj = 0; nj < 2; ++nj)                                     \
        _Pragma("unroll")                                                  \
        for (int i = 0; i < 16; ++i) {                                     \
            float d = win[nj][i];                                          \
            float e = __expf(fabsf(d));                                    \
            den[nj][i] += e;                                               \
            num[nj][i] = fmaf(e, d, num[nj][i]);                           \
        }                                                                  \
    } while (0)

    short8 xh0a, xh1a, xl0a, xl1a, xh0b, xh1b, xl0b, xl1b;

    LOADX(xh0a, xh1a, xl0a, xl1a, 0);
    STAGE(0, 0);
    __syncthreads();

#pragma unroll 1
    for (int w = 0; w < 32; ++w) {
        const int t0 = 2 * w;
        STAGE(1, t0 + 1);
        LOADX(xh0b, xh1b, xl0b, xl1b, t0 + 1);
        COMPUTE(0, xh0a, xh1a, xl0a, xl1a, true);
        __syncthreads();
        if (t0 + 2 < 64) {
            STAGE(0, t0 + 2);
            LOADX(xh0a, xh1a, xl0a, xl1a, t0 + 2);
        }
        COMPUTE(1, xh0b, xh1b, xl0b, xl1b, false);
        EPILOG();
        __syncthreads();
    }

    // Final epilogue. C/D 32x32: col = lane&31, row = (i&3)+8*(i>>2)+4*(lane>>5)
#pragma unroll
    for (int nj = 0; nj < 2; ++nj)
#pragma unroll
        for (int i = 0; i < 16; ++i) {
            float gg   = num[nj][i] / den[nj][i];
            float gate = gg / (1.0f + __expf(-gg));
            float val  = gate * lin[nj][i];
            int r = row0 + wm * 32 + (i & 3) + 8 * (i >> 2) + 4 * (lane >> 5);
            int c = col0 + wn * 64 + nj * 32 + (lane & 31);
            O[(size_t)r * H_DIM + c] = val;
        }
#undef STAGE
#undef LOADX
#undef COMPUTE
#undef EPILOG
}

// ------------------------------------------------- fallback (round-1 path) --
__global__ __launch_bounds__(512) void dend_fused_v0(
    const float* __restrict__ X, const float* __restrict__ T,
    const float* __restrict__ W, float* __restrict__ O)
{
    __shared__ __align__(16) short lds[2][5][128 * BK];

    const int tid  = threadIdx.x;
    const int lane = tid & 63;
    const int wv   = tid >> 6;
    const int wm   = wv >> 2;
    const int wn   = wv & 3;

    const int bid     = blockIdx.x;
    const int logical = (bid & 7) * 32 + (bid >> 3);
    const int hb   = logical >> 5;
    const int nb   = logical & 31;
    const int row0 = nb * 128;
    const int col0 = hb * 128;

    const int srow  = tid >> 2;
    const int schn  = tid & 3;
    const int sslot = schn ^ ((srow >> 1) & 3);
    const int swoff = srow * BK + sslot * 8;

    const float* gx = X + (size_t)(row0 + srow) * K_DIM + schn * 8;
    const float* gw = W + (size_t)(col0 + srow) * K_DIM + schn * 8;
    const float* gt = T + (size_t)(col0 + srow) * K_DIM + schn * 8;

    const int g = lane >> 4;
    int a_off[4], b_off[2];
#pragma unroll
    for (int mi = 0; mi < 4; ++mi) {
        int r = wm * 64 + mi * 16 + (lane & 15);
        a_off[mi] = r * BK + (g ^ ((r >> 1) & 3)) * 8;
    }
#pragma unroll
    for (int nj = 0; nj < 2; ++nj) {
        int r = wn * 32 + nj * 16 + (lane & 15);
        b_off[nj] = r * BK + (g ^ ((r >> 1) & 3)) * 8;
    }

    const f32x4 zeroc = (f32x4)0.0f;
    f32x4 lin[4][2], num[4][2], den[4][2], win[4][2];
#pragma unroll
    for (int mi = 0; mi < 4; ++mi)
#pragma unroll
        for (int nj = 0; nj < 2; ++nj) {
            lin[mi][nj] = zeroc; num[mi][nj] = zeroc; den[mi][nj] = zeroc;
        }

    f32x4 rx0, rx1, rw0, rw1, rt0, rt1;

#define LOADS(t) do {                                                   \
        const float* px = gx + (size_t)(t) * BK;                        \
        const float* pw = gw + (size_t)(t) * BK;                        \
        const float* pt = gt + (size_t)(t) * BK;                        \
        rx0 = *(const f32x4*)(px); rx1 = *(const f32x4*)(px + 4);       \
        rw0 = *(const f32x4*)(pw); rw1 = *(const f32x4*)(pw + 4);       \
        rt0 = *(const f32x4*)(pt); rt1 = *(const f32x4*)(pt + 4);       \
    } while (0)

#define WRITE(buf) do {                                                 \
        short8 vh, vl;                                                  \
        cvt_split(rx0, rx1, vh, vl);                                    \
        *(short8*)&lds[buf][0][swoff] = vh;                             \
        *(short8*)&lds[buf][1][swoff] = vl;                             \
        cvt_split(rw0, rw1, vh, vl);                                    \
        *(short8*)&lds[buf][2][swoff] = vh;                             \
        *(short8*)&lds[buf][3][swoff] = vl;                             \
        *(short8*)&lds[buf][4][swoff] = cvt_hi(rt0, rt1);               \
    } while (0)

#define COMPUTE(buf, ZW) do {                                           \
        short8 bwh[2], bwl[2], bth[2];                                  \
        _Pragma("unroll")                                               \
        for (int nj = 0; nj < 2; ++nj) {                                \
            bwh[nj] = *(const short8*)&lds[buf][2][b_off[nj]];          \
            bwl[nj] = *(const short8*)&lds[buf][3][b_off[nj]];          \
            bth[nj] = *(const short8*)&lds[buf][4][b_off[nj]];          \
        }                                                               \
        _Pragma("unroll")                                               \
        for (int mi = 0; mi < 4; ++mi) {                                \
            short8 ah = *(const short8*)&lds[buf][0][a_off[mi]];        \
            short8 al = *(const short8*)&lds[buf][1][a_off[mi]];        \
            _Pragma("unroll")                                           \
            for (int nj = 0; nj < 2; ++nj) {                            \
                lin[mi][nj] = MFMA16(ah, bwh[nj], lin[mi][nj]);         \
                lin[mi][nj] = MFMA16(al, bwh[nj], lin[mi][nj]);         \
                lin[mi][nj] = MFMA16(ah, bwl[nj], lin[mi][nj]);         \
                win[mi][nj] = MFMA16(ah, bth[nj], (ZW) ? zeroc : win[mi][nj]); \
            }                                                           \
        }                                                               \
    } while (0)

#define EPILOG() do {                                                   \
        _Pragma("unroll")                                               \
        for (int mi = 0; mi < 4; ++mi)                                  \
        _Pragma("unroll")                                               \
        for (int nj = 0; nj < 2; ++nj)                                  \
        _Pragma("unroll")                                               \
        for (int i = 0; i < 4; ++i) {                                   \
            float d = win[mi][nj][i];                                   \
            float e = __expf(fabsf(d));                                 \
            den[mi][nj][i] += e;                                        \
            num[mi][nj][i] = fmaf(e, d, num[mi][nj][i]);                \
        }                                                               \
    } while (0)

    LOADS(0);
    WRITE(0);
    __syncthreads();

#pragma unroll 1
    for (int w = 0; w < 32; ++w) {
        const int t0 = 2 * w;
        LOADS(t0 + 1);
        COMPUTE(0, true);
        __syncthreads();
        WRITE(1);
        __syncthreads();
        const bool more = (w < 31);
        if (more) LOADS(t0 + 2);
        COMPUTE(1, false);
        EPILOG();
        __syncthreads();
        if (more) WRITE(0);
        __syncthreads();
    }

#pragma unroll
    for (int mi = 0; mi < 4; ++mi)
#pragma unroll
        for (int nj = 0; nj < 2; ++nj)
#pragma unroll
            for (int i = 0; i < 4; ++i) {
                float gg   = num[mi][nj][i] / den[mi][nj][i];
                float gate = gg / (1.0f + __expf(-gg));
                float val  = gate * lin[mi][nj][i];
                int r = row0 + wm * 64 + mi * 16 + (lane >> 4) * 4 + i;
                int c = col0 + wn * 32 + nj * 16 + (lane & 15);
                O[(size_t)r * H_DIM + c] = val;
            }
#undef LOADS
#undef WRITE
#undef COMPUTE
#undef EPILOG
}

extern "C" void kernel_launch(void* const* d_in, const int* in_sizes, int n_in,
                              void* d_out, int out_size, void* d_ws, size_t ws_size,
                              hipStream_t stream) {
    const float* X = (const float*)d_in[0];   // x [4096,2048]
    const float* T = (const float*)d_in[1];   // template_flat [1024,2048]
    const float* W = (const float*)d_in[2];   // weights [1024,2048]
    float* O = (float*)d_out;                 // [4096,1024]
    (void)in_sizes; (void)n_in; (void)out_size;

    if (ws_size >= WS_NEED) {
        unsigned short* XHp = (unsigned short*)d_ws;
        unsigned short* XLp = XHp + X_ELEMS;
        unsigned short* WHp = XLp + X_ELEMS;
        unsigned short* WLp = WHp + W_ELEMS;
        unsigned short* THp = WLp + W_ELEMS;
        prepass_all<<<XB + 2 * WB, 256, 0, stream>>>(X, W, T, XHp, XLp, WHp, WLp, THp);
        dend_gemm<<<256, 512, 0, stream>>>(XHp, XLp, WHp, WLp, THp, O);
    } else {
        dend_fused_v0<<<256, 512, 0, stream>>>(X, T, W, O);
    }
}

// Round 6
// 114.864 us; speedup vs baseline: 1.4456x; 1.4456x over previous
//
#include <hip/hip_runtime.h>
#include <hip/hip_bf16.h>

// DendriticLayerSiLU: out = silu(softmax-gated template proj) * (x @ W^T)
// N=4096 tokens, K=2048, H=1024, 32 windows of 64.
// Round 6: r4 geometry (64x128 tile, validated conflict-free layout) +
// r3 pipeline discipline (4-deep LDS, counted vmcnt(8), raw s_barrier,
// never drain in-loop). 128 KB LDS, 1 block/CU, acc only 64 regs (no spill).

typedef __attribute__((ext_vector_type(8))) short short8;
typedef __attribute__((ext_vector_type(4))) float f32x4;

#define N_TOK 4096
#define K_DIM 2048
#define H_DIM 1024
#define BM 64
#define BH 128
#define BK 32

#define X_ELEMS (N_TOK * K_DIM)   // 8388608
#define W_ELEMS (H_DIM * K_DIM)   // 2097152
#define WS_NEED ((size_t)(2 * X_ELEMS + 3 * W_ELEMS) * 2)  // 46,137,344 B

#define XB (X_ELEMS / 8 / 256)    // 4096 prepass blocks for X
#define WB (W_ELEMS / 8 / 256)    // 1024 for W, 1024 for T

__device__ __forceinline__ unsigned short f2bf(float f) {
    unsigned int u = __float_as_uint(f);
    u += 0x7FFFu + ((u >> 16) & 1u);    // round-to-nearest-even
    return (unsigned short)(u >> 16);
}
__device__ __forceinline__ float bf2f(unsigned short h) {
    return __uint_as_float(((unsigned int)h) << 16);
}

__device__ __forceinline__ void cvt_split(f32x4 a, f32x4 b, short8& vh, short8& vl) {
#pragma unroll
    for (int i = 0; i < 4; ++i) {
        float f = a[i];
        unsigned short h = f2bf(f);
        vh[i] = (short)h;
        vl[i] = (short)f2bf(f - bf2f(h));
    }
#pragma unroll
    for (int i = 0; i < 4; ++i) {
        float f = b[i];
        unsigned short h = f2bf(f);
        vh[i + 4] = (short)h;
        vl[i + 4] = (short)f2bf(f - bf2f(h));
    }
}
__device__ __forceinline__ short8 cvt_hi(f32x4 a, f32x4 b) {
    short8 v;
#pragma unroll
    for (int i = 0; i < 4; ++i) { v[i] = (short)f2bf(a[i]); v[i + 4] = (short)f2bf(b[i]); }
    return v;
}

#define MFMA16(A, B, C) __builtin_amdgcn_mfma_f32_16x16x32_bf16(A, B, C, 0, 0, 0)

// ---------------------------------------------------------------- prepass ---
__global__ __launch_bounds__(256) void prepass_all(
    const float* __restrict__ X, const float* __restrict__ W,
    const float* __restrict__ T,
    unsigned short* __restrict__ XH, unsigned short* __restrict__ XL,
    unsigned short* __restrict__ WH, unsigned short* __restrict__ WL,
    unsigned short* __restrict__ TH)
{
    int b = blockIdx.x;
    if (b < XB + WB) {
        const float* src; unsigned short *hi, *lo; int i;
        if (b < XB) { src = X; hi = XH; lo = XL; i = b * 256 + threadIdx.x; }
        else        { src = W; hi = WH; lo = WL; i = (b - XB) * 256 + threadIdx.x; }
        const float* p = src + (size_t)i * 8;
        f32x4 a = *(const f32x4*)p;
        f32x4 c = *(const f32x4*)(p + 4);
        short8 vh, vl;
        cvt_split(a, c, vh, vl);
        *(short8*)&hi[(size_t)i * 8] = vh;
        *(short8*)&lo[(size_t)i * 8] = vl;
    } else {
        int i = (b - XB - WB) * 256 + threadIdx.x;
        const float* p = T + (size_t)i * 8;
        f32x4 a = *(const f32x4*)p;
        f32x4 c = *(const f32x4*)(p + 4);
        *(short8*)&TH[(size_t)i * 8] = cvt_hi(a, c);
    }
}

// ------------------------------------------------------------- main GEMM ----
#define GLL(gp, lp) __builtin_amdgcn_global_load_lds(                      \
        (const __attribute__((address_space(1))) void*)(gp),               \
        (__attribute__((address_space(3))) void*)(lp), 16, 0, 0)

// counted-vmcnt barrier: N loads stay in flight across the barrier (T4).
#define VMBAR(N) do {                                                      \
        asm volatile("s_waitcnt vmcnt(" #N ")" ::: "memory");              \
        __builtin_amdgcn_s_barrier();                                      \
        asm volatile("" ::: "memory");                                     \
    } while (0)

__global__ __launch_bounds__(512) void dend_gemm(
    const unsigned short* __restrict__ XH, const unsigned short* __restrict__ XL,
    const unsigned short* __restrict__ WH, const unsigned short* __restrict__ WL,
    const unsigned short* __restrict__ TH, float* __restrict__ O)
{
    // 4-deep pipeline: X 2 arrays [64][32], W/T 3 arrays [128][32] = 128 KB
    __shared__ __align__(16) short ldsx[4][2][BM * BK];   // 32 KB
    __shared__ __align__(16) short ldsw[4][3][BH * BK];   // 96 KB

    const int tid  = threadIdx.x;
    const int lane = tid & 63;
    const int wv   = tid >> 6;    // 0..7
    const int wm   = wv >> 2;     // 0..1  (32 token-rows each)
    const int wn   = wv & 3;      // 0..3  (32 units each)

    // grid 512 = 64 row-blocks x 8 col-panels; XCD k owns panel k
    const int bid     = blockIdx.x;
    const int logical = (bid & 7) * 64 + (bid >> 3);
    const int hb   = logical >> 6;   // 0..7
    const int nb   = logical & 63;   // 0..63
    const int row0 = nb * BM;
    const int col0 = hb * BH;

    // Staging (validated r4 layout): GLL linear dest; pre-swizzled global
    // source so slot s of row r holds chunk s ^ ((r>>1)&3).
    const int sc   = (lane & 3) ^ ((lane >> 3) & 3);
    const unsigned short* xsrc = (wv < 4) ? XH : XL;
    const int xarr = wv >> 2;                       // 0=hi 1=lo
    const int xrow = (wv & 3) * 16 + (lane >> 2);   // 0..63
    const int wrow = wv * 16 + (lane >> 2);         // 0..127
    const size_t xbase = (size_t)(row0 + xrow) * K_DIM + sc * 8;
    const size_t wbase = (size_t)(col0 + wrow) * K_DIM + sc * 8;

#define STAGE(buf, t) do {                                                 \
        const size_t ko = (size_t)(t) * BK;                                \
        GLL(xsrc + xbase + ko, &ldsx[buf][xarr][(wv & 3) << 9]);           \
        GLL(WH + wbase + ko, &ldsw[buf][0][wv << 9]);                      \
        GLL(WL + wbase + ko, &ldsw[buf][1][wv << 9]);                      \
        GLL(TH + wbase + ko, &ldsw[buf][2][wv << 9]);                      \
    } while (0)

    // Fragment read offsets (validated swizzle, 0 conflicts in r1-r4)
    const int g = lane >> 4;
    int a_off[2], b_off[2];
#pragma unroll
    for (int mi = 0; mi < 2; ++mi) {
        int r = wm * 32 + mi * 16 + (lane & 15);    // 0..63
        a_off[mi] = r * BK + (g ^ ((r >> 1) & 3)) * 8;
    }
#pragma unroll
    for (int nj = 0; nj < 2; ++nj) {
        int r = wn * 32 + nj * 16 + (lane & 15);    // 0..127
        b_off[nj] = r * BK + (g ^ ((r >> 1) & 3)) * 8;
    }

    const f32x4 zeroc = (f32x4)0.0f;
    f32x4 lin[2][2], num[2][2], den[2][2], win[2][2];
#pragma unroll
    for (int mi = 0; mi < 2; ++mi)
#pragma unroll
        for (int nj = 0; nj < 2; ++nj) {
            lin[mi][nj] = zeroc; num[mi][nj] = zeroc; den[mi][nj] = zeroc;
        }

#define COMPUTE(buf, ZW) do {                                              \
        short8 bwh[2], bwl[2], bth[2];                                     \
        _Pragma("unroll")                                                  \
        for (int nj = 0; nj < 2; ++nj) {                                   \
            bwh[nj] = *(const short8*)&ldsw[buf][0][b_off[nj]];            \
            bwl[nj] = *(const short8*)&ldsw[buf][1][b_off[nj]];            \
            bth[nj] = *(const short8*)&ldsw[buf][2][b_off[nj]];            \
        }                                                                  \
        _Pragma("unroll")                                                  \
        for (int mi = 0; mi < 2; ++mi) {                                   \
            short8 ah = *(const short8*)&ldsx[buf][0][a_off[mi]];          \
            short8 al = *(const short8*)&ldsx[buf][1][a_off[mi]];          \
            _Pragma("unroll")                                              \
            for (int nj = 0; nj < 2; ++nj) {                               \
                lin[mi][nj] = MFMA16(ah, bwh[nj], lin[mi][nj]);            \
                lin[mi][nj] = MFMA16(al, bwh[nj], lin[mi][nj]);            \
                lin[mi][nj] = MFMA16(ah, bwl[nj], lin[mi][nj]);            \
                win[mi][nj] = MFMA16(ah, bth[nj], (ZW) ? zeroc : win[mi][nj]); \
            }                                                              \
        }                                                                  \
    } while (0)

#define EPILOG() do {                                                      \
        _Pragma("unroll")                                                  \
        for (int mi = 0; mi < 2; ++mi)                                     \
        _Pragma("unroll")                                                  \
        for (int nj = 0; nj < 2; ++nj)                                     \
        _Pragma("unroll")                                                  \
        for (int i = 0; i < 4; ++i) {                                      \
            float d = win[mi][nj][i];                                      \
            float e = __expf(fabsf(d));                                    \
            den[mi][nj][i] += e;                                           \
            num[mi][nj][i] = fmaf(e, d, num[mi][nj][i]);                   \
        }                                                                  \
    } while (0)

    // Prologue: 2 tiles in flight before the first wait.
    STAGE(0, 0);
    STAGE(1, 1);

    // Steady state: stage t+2, wait to 8 outstanding (tiles t+1,t+2 remain
    // in flight across the barrier), compute tile t. One barrier per step;
    // buffer write-after-read separated by one barrier (validated in r3).
#pragma unroll 1
    for (int t = 0; t < 60; t += 4) {
        STAGE(2, t + 2); VMBAR(8); COMPUTE(0, true);
        STAGE(3, t + 3); VMBAR(8); COMPUTE(1, false); EPILOG();
        STAGE(0, t + 4); VMBAR(8); COMPUTE(2, true);
        STAGE(1, t + 5); VMBAR(8); COMPUTE(3, false); EPILOG();
    }
    // Tail: tiles 60..63 (stages 62,63 only), draining vmcnt 8 -> 4 -> 0.
    STAGE(2, 62); VMBAR(8); COMPUTE(0, true);
    STAGE(3, 63); VMBAR(8); COMPUTE(1, false); EPILOG();
    VMBAR(4); COMPUTE(2, true);
    VMBAR(0); COMPUTE(3, false); EPILOG();

    // Final epilogue: g = num/den, silu, multiply, store.
#pragma unroll
    for (int mi = 0; mi < 2; ++mi)
#pragma unroll
        for (int nj = 0; nj < 2; ++nj)
#pragma unroll
            for (int i = 0; i < 4; ++i) {
                float gg   = num[mi][nj][i] / den[mi][nj][i];
                float gate = gg / (1.0f + __expf(-gg));
                float val  = gate * lin[mi][nj][i];
                int r = row0 + wm * 32 + mi * 16 + (lane >> 4) * 4 + i;
                int c = col0 + wn * 32 + nj * 16 + (lane & 15);
                O[(size_t)r * H_DIM + c] = val;
            }
#undef STAGE
#undef COMPUTE
#undef EPILOG
}

// ------------------------------------------------- fallback (round-1 path) --
__global__ __launch_bounds__(512) void dend_fused_v0(
    const float* __restrict__ X, const float* __restrict__ T,
    const float* __restrict__ W, float* __restrict__ O)
{
    __shared__ __align__(16) short lds[2][5][128 * BK];

    const int tid  = threadIdx.x;
    const int lane = tid & 63;
    const int wv   = tid >> 6;
    const int wm   = wv >> 2;
    const int wn   = wv & 3;

    const int bid     = blockIdx.x;
    const int logical = (bid & 7) * 32 + (bid >> 3);
    const int hb   = logical >> 5;
    const int nb   = logical & 31;
    const int row0 = nb * 128;
    const int col0 = hb * 128;

    const int srow  = tid >> 2;
    const int schn  = tid & 3;
    const int sslot = schn ^ ((srow >> 1) & 3);
    const int swoff = srow * BK + sslot * 8;

    const float* gx = X + (size_t)(row0 + srow) * K_DIM + schn * 8;
    const float* gw = W + (size_t)(col0 + srow) * K_DIM + schn * 8;
    const float* gt = T + (size_t)(col0 + srow) * K_DIM + schn * 8;

    const int g = lane >> 4;
    int a_off[4], b_off[2];
#pragma unroll
    for (int mi = 0; mi < 4; ++mi) {
        int r = wm * 64 + mi * 16 + (lane & 15);
        a_off[mi] = r * BK + (g ^ ((r >> 1) & 3)) * 8;
    }
#pragma unroll
    for (int nj = 0; nj < 2; ++nj) {
        int r = wn * 32 + nj * 16 + (lane & 15);
        b_off[nj] = r * BK + (g ^ ((r >> 1) & 3)) * 8;
    }

    const f32x4 zeroc = (f32x4)0.0f;
    f32x4 lin[4][2], num[4][2], den[4][2], win[4][2];
#pragma unroll
    for (int mi = 0; mi < 4; ++mi)
#pragma unroll
        for (int nj = 0; nj < 2; ++nj) {
            lin[mi][nj] = zeroc; num[mi][nj] = zeroc; den[mi][nj] = zeroc;
        }

    f32x4 rx0, rx1, rw0, rw1, rt0, rt1;

#define LOADS(t) do {                                                   \
        const float* px = gx + (size_t)(t) * BK;                        \
        const float* pw = gw + (size_t)(t) * BK;                        \
        const float* pt = gt + (size_t)(t) * BK;                        \
        rx0 = *(const f32x4*)(px); rx1 = *(const f32x4*)(px + 4);       \
        rw0 = *(const f32x4*)(pw); rw1 = *(const f32x4*)(pw + 4);       \
        rt0 = *(const f32x4*)(pt); rt1 = *(const f32x4*)(pt + 4);       \
    } while (0)

#define WRITE(buf) do {                                                 \
        short8 vh, vl;                                                  \
        cvt_split(rx0, rx1, vh, vl);                                    \
        *(short8*)&lds[buf][0][swoff] = vh;                             \
        *(short8*)&lds[buf][1][swoff] = vl;                             \
        cvt_split(rw0, rw1, vh, vl);                                    \
        *(short8*)&lds[buf][2][swoff] = vh;                             \
        *(short8*)&lds[buf][3][swoff] = vl;                             \
        *(short8*)&lds[buf][4][swoff] = cvt_hi(rt0, rt1);               \
    } while (0)

#define COMPUTE(buf, ZW) do {                                           \
        short8 bwh[2], bwl[2], bth[2];                                  \
        _Pragma("unroll")                                               \
        for (int nj = 0; nj < 2; ++nj) {                                \
            bwh[nj] = *(const short8*)&lds[buf][2][b_off[nj]];          \
            bwl[nj] = *(const short8*)&lds[buf][3][b_off[nj]];          \
            bth[nj] = *(const short8*)&lds[buf][4][b_off[nj]];          \
        }                                                               \
        _Pragma("unroll")                                               \
        for (int mi = 0; mi < 4; ++mi) {                                \
            short8 ah = *(const short8*)&lds[buf][0][a_off[mi]];        \
            short8 al = *(const short8*)&lds[buf][1][a_off[mi]];        \
            _Pragma("unroll")                                           \
            for (int nj = 0; nj < 2; ++nj) {                            \
                lin[mi][nj] = MFMA16(ah, bwh[nj], lin[mi][nj]);         \
                lin[mi][nj] = MFMA16(al, bwh[nj], lin[mi][nj]);         \
                lin[mi][nj] = MFMA16(ah, bwl[nj], lin[mi][nj]);         \
                win[mi][nj] = MFMA16(ah, bth[nj], (ZW) ? zeroc : win[mi][nj]); \
            }                                                           \
        }                                                               \
    } while (0)

#define EPILOG() do {                                                   \
        _Pragma("unroll")                                               \
        for (int mi = 0; mi < 4; ++mi)                                  \
        _Pragma("unroll")                                               \
        for (int nj = 0; nj < 2; ++nj)                                  \
        _Pragma("unroll")                                               \
        for (int i = 0; i < 4; ++i) {                                   \
            float d = win[mi][nj][i];                                   \
            float e = __expf(fabsf(d));                                 \
            den[mi][nj][i] += e;                                        \
            num[mi][nj][i] = fmaf(e, d, num[mi][nj][i]);                \
        }                                                               \
    } while (0)

    LOADS(0);
    WRITE(0);
    __syncthreads();

#pragma unroll 1
    for (int w = 0; w < 32; ++w) {
        const int t0 = 2 * w;
        LOADS(t0 + 1);
        COMPUTE(0, true);
        __syncthreads();
        WRITE(1);
        __syncthreads();
        const bool more = (w < 31);
        if (more) LOADS(t0 + 2);
        COMPUTE(1, false);
        EPILOG();
        __syncthreads();
        if (more) WRITE(0);
        __syncthreads();
    }

#pragma unroll
    for (int mi = 0; mi < 4; ++mi)
#pragma unroll
        for (int nj = 0; nj < 2; ++nj)
#pragma unroll
            for (int i = 0; i < 4; ++i) {
                float gg   = num[mi][nj][i] / den[mi][nj][i];
                float gate = gg / (1.0f + __expf(-gg));
                float val  = gate * lin[mi][nj][i];
                int r = row0 + wm * 64 + mi * 16 + (lane >> 4) * 4 + i;
                int c = col0 + wn * 32 + nj * 16 + (lane & 15);
                O[(size_t)r * H_DIM + c] = val;
            }
#undef LOADS
#undef WRITE
#undef COMPUTE
#undef EPILOG
}

extern "C" void kernel_launch(void* const* d_in, const int* in_sizes, int n_in,
                              void* d_out, int out_size, void* d_ws, size_t ws_size,
                              hipStream_t stream) {
    const float* X = (const float*)d_in[0];   // x [4096,2048]
    const float* T = (const float*)d_in[1];   // template_flat [1024,2048]
    const float* W = (const float*)d_in[2];   // weights [1024,2048]
    float* O = (float*)d_out;                 // [4096,1024]
    (void)in_sizes; (void)n_in; (void)out_size;

    if (ws_size >= WS_NEED) {
        unsigned short* XHp = (unsigned short*)d_ws;
        unsigned short* XLp = XHp + X_ELEMS;
        unsigned short* WHp = XLp + X_ELEMS;
        unsigned short* WLp = WHp + W_ELEMS;
        unsigned short* THp = WLp + W_ELEMS;
        prepass_all<<<XB + 2 * WB, 256, 0, stream>>>(X, W, T, XHp, XLp, WHp, WLp, THp);
        dend_gemm<<<512, 512, 0, stream>>>(XHp, XLp, WHp, WLp, THp, O);
    } else {
        dend_fused_v0<<<256, 512, 0, stream>>>(X, T, W, O);
    }
}